// Round 1
// baseline (449.127 us; speedup 1.0000x reference)
//
#include <hip/hip_runtime.h>
#include <hip/hip_bf16.h>

// CausalSelfAttention: B=4, S=2048, D=1024, H=16, Dh=64. fp32 in/out, bf16 MFMA compute.
//
// Pipeline (all on `stream`):
//   1. convert_x: x fp32 -> bf16 (8192x1024)
//   2. transpose_w: Wq|Wk -> wqkt (2048x1024 bf16, N-major), Wv -> wvt, Wo -> wot
//   3. pack_bqk: [bq|bk] -> bqk fp32 (2048)
//   4. gemm<0>: qk = xb @ [Wq|Wk] + bqk   -> bf16 (8192 x 2048), q cols 0..1023, k cols 1024..2047
//   5. gemm<2>: vt = (xb @ Wv + bv)^T     -> bf16 (B,H,Dh,S) scatter epilogue
//   6. attn: causal flash attention, BM=BN=64 -> attn bf16 (8192 x 1024)
//   7. gemm<1>: out = attn @ Wo + bo      -> fp32 d_out

typedef __bf16 bf16x8 __attribute__((ext_vector_type(8)));
typedef float f32x4 __attribute__((ext_vector_type(4)));
typedef unsigned short u16;

__device__ __forceinline__ u16 f2b(float f) {
    __hip_bfloat16 h = __float2bfloat16(f);
    return __builtin_bit_cast(unsigned short, h);
}

__device__ __forceinline__ f32x4 mfma16(bf16x8 a, bf16x8 b, f32x4 c) {
    return __builtin_amdgcn_mfma_f32_16x16x32_bf16(a, b, c, 0, 0, 0);
}

typedef const __attribute__((address_space(1))) unsigned int* gas1_t;
typedef __attribute__((address_space(3))) unsigned int* las3_t;
// Async global->LDS, 16B per lane. LDS dest = wave-uniform base + lane*16 (m104/m108).
__device__ __forceinline__ void gld16(const void* g, void* l) {
    __builtin_amdgcn_global_load_lds((gas1_t)g, (las3_t)l, 16, 0, 0);
}

// ---------------------------------------------------------------- conversions
__global__ __launch_bounds__(256) void convert_x(const float* __restrict__ x,
                                                 u16* __restrict__ xb, int n4) {
    int i = blockIdx.x * 256 + threadIdx.x;
    if (i < n4) {
        float4 v = ((const float4*)x)[i];
        ushort4 u;
        u.x = f2b(v.x); u.y = f2b(v.y); u.z = f2b(v.z); u.w = f2b(v.w);
        ((ushort4*)xb)[i] = u;
    }
}

// W (K=1024 rows, N=1024 cols) fp32 -> Wt (N,K) bf16. z selects matrix.
__global__ __launch_bounds__(256) void transpose_w(const float* __restrict__ Wq,
                                                   const float* __restrict__ Wk,
                                                   const float* __restrict__ Wv,
                                                   const float* __restrict__ Wo,
                                                   u16* __restrict__ wqkt,
                                                   u16* __restrict__ wvt,
                                                   u16* __restrict__ wot) {
    const int z = blockIdx.z;
    const float* src = (z == 0) ? Wq : (z == 1) ? Wk : (z == 2) ? Wv : Wo;
    u16* dst = (z == 0) ? wqkt : (z == 1) ? (wqkt + 1024 * 1024) : (z == 2) ? wvt : wot;
    __shared__ float tile[32][33];
    const int tx = threadIdx.x, ty = threadIdx.y;  // block (32,8)
    const int nbase = blockIdx.x * 32, kbase = blockIdx.y * 32;
    for (int j = 0; j < 4; ++j)
        tile[ty + j * 8][tx] = src[(size_t)(kbase + ty + j * 8) * 1024 + nbase + tx];
    __syncthreads();
    for (int j = 0; j < 4; ++j)
        dst[(size_t)(nbase + ty + j * 8) * 1024 + kbase + tx] = f2b(tile[tx][ty + j * 8]);
}

__global__ __launch_bounds__(256) void pack_bqk(const float* __restrict__ bq,
                                                const float* __restrict__ bk,
                                                float* __restrict__ bqk) {
    int i = blockIdx.x * 256 + threadIdx.x;  // 2048 total
    bqk[i] = (i < 1024) ? bq[i] : bk[i - 1024];
}

// ---------------------------------------------------------------- GEMM (m97-style)
// C(M,N) = A(M,K) @ Bt(N,K)^T + bias. 128x128 tile, BK=32, 256 thr = 4 waves,
// each wave a 64x64 quadrant of 4x4 16x16x32 MFMAs.
// MODE 0: bf16 row-major out (ldc). MODE 1: fp32 row-major out (ldc).
// MODE 2: bf16 V^T scatter: out[((tok/2048)*16 + n/64)*64 + n%64][2048] col tok%2048.
template <int MODE>
__global__ __launch_bounds__(256) void gemm_bt(const u16* __restrict__ A,
                                               const u16* __restrict__ Bt,
                                               const float* __restrict__ bias,
                                               void* __restrict__ Cout,
                                               int M, int N, int K, int ldc) {
    const int tid = threadIdx.x;
    const int l = tid & 63;
    const int w = tid >> 6;
    const int tileM = blockIdx.x * 128;
    const int tileN = blockIdx.y * 128;

    __shared__ u16 As[128 * 32];  // [row][k] stride 32 (contiguous: global_load_lds)
    __shared__ u16 Bs[128 * 32];

    const int srow = l >> 2;      // staging row within 16-row segment
    const int schunk = l & 3;     // staging k-chunk (8 bf16 = 16B)
    const int mrow = l & 15;
    const int g8 = (l >> 4) * 8;
    const int waveM = (w & 1) * 64;
    const int waveN = (w >> 1) * 64;

    f32x4 acc[4][4] = {};

    for (int k0 = 0; k0 < K; k0 += 32) {
        // stage: wave w handles A rows [tileM+w*32, +32) and Bt rows [tileN+w*32, +32)
        gld16(A + (size_t)(tileM + w * 32 + srow) * K + k0 + schunk * 8, &As[(w * 2) * 512]);
        gld16(A + (size_t)(tileM + w * 32 + 16 + srow) * K + k0 + schunk * 8, &As[(w * 2 + 1) * 512]);
        gld16(Bt + (size_t)(tileN + w * 32 + srow) * K + k0 + schunk * 8, &Bs[(w * 2) * 512]);
        gld16(Bt + (size_t)(tileN + w * 32 + 16 + srow) * K + k0 + schunk * 8, &Bs[(w * 2 + 1) * 512]);
        __syncthreads();

        bf16x8 af[4], bf[4];
        for (int im = 0; im < 4; ++im)
            af[im] = *(const bf16x8*)&As[(waveM + im * 16 + mrow) * 32 + g8];
        for (int in = 0; in < 4; ++in)
            bf[in] = *(const bf16x8*)&Bs[(waveN + in * 16 + mrow) * 32 + g8];
        for (int im = 0; im < 4; ++im)
            for (int in = 0; in < 4; ++in)
                acc[im][in] = mfma16(af[im], bf[in], acc[im][in]);
        __syncthreads();
    }

    // epilogue. C/D layout: row=(l>>4)*4+r, col=l&15  [m89/m91]
    const int rbase = (l >> 4) * 4;
    for (int im = 0; im < 4; ++im) {
        for (int in = 0; in < 4; ++in) {
            const int gm0 = tileM + waveM + im * 16 + rbase;
            const int gn = tileN + waveN + in * 16 + (l & 15);
            const float bv_ = bias[gn];
            if (MODE == 0) {
                u16* out = (u16*)Cout;
                for (int r = 0; r < 4; ++r)
                    out[(size_t)(gm0 + r) * ldc + gn] = f2b(acc[im][in][r] + bv_);
            } else if (MODE == 1) {
                float* out = (float*)Cout;
                for (int r = 0; r < 4; ++r)
                    out[(size_t)(gm0 + r) * ldc + gn] = acc[im][in][r] + bv_;
            } else {
                // V^T scatter: 4 consecutive tokens (rows) -> contiguous s, one ushort4
                u16* out = (u16*)Cout;
                const int b = gm0 >> 11, s0 = gm0 & 2047;
                const int h = gn >> 6, dh = gn & 63;
                ushort4 u;
                u.x = f2b(acc[im][in][0] + bv_);
                u.y = f2b(acc[im][in][1] + bv_);
                u.z = f2b(acc[im][in][2] + bv_);
                u.w = f2b(acc[im][in][3] + bv_);
                *(ushort4*)&out[((size_t)((b * 16 + h) * 64 + dh)) * 2048 + s0] = u;
            }
        }
    }
}

// ---------------------------------------------------------------- flash attention
// grid (32 qtiles, 64 bh). 256 thr = 4 waves, wave w owns Q rows [q0+w*16, +16).
// LDS tiles padded to stride 72 elements (144 B, 16B-aligned) to break bank-period.
__global__ __launch_bounds__(256) void attn_kernel(const u16* __restrict__ qk,
                                                   const u16* __restrict__ vt,
                                                   u16* __restrict__ attn) {
    const int qt = blockIdx.x;
    const int bh = blockIdx.y;
    const int b = bh >> 4, h = bh & 15;
    const int q0 = qt * 64;
    const int tid = threadIdx.x, l = tid & 63, w = tid >> 6;
    const int mrow = l & 15, g8 = (l >> 4) * 8;

    __shared__ u16 Ks[64 * 72];  // [key][dh]
    __shared__ u16 Vs[64 * 72];  // [dh][key] (from vt global)
    __shared__ u16 Ps[64 * 72];  // Q staging, then per-wave P slabs (rows w*16..w*16+15)

    // stage Q tile (rows q0..q0+63, cols h*64..h*64+63) into Ps
    for (int i = 0; i < 2; ++i) {
        const int idx = i * 256 + tid;
        const int row = idx >> 3, ch = idx & 7;
        *(uint4*)&Ps[row * 72 + ch * 8] =
            *(const uint4*)&qk[(size_t)(b * 2048 + q0 + row) * 2048 + h * 64 + ch * 8];
    }
    __syncthreads();
    bf16x8 qa[2];
    qa[0] = *(const bf16x8*)&Ps[(w * 16 + mrow) * 72 + g8];
    qa[1] = *(const bf16x8*)&Ps[(w * 16 + mrow) * 72 + 32 + g8];

    float m_i[4], l_i[4];
    f32x4 o[4] = {};
    for (int r = 0; r < 4; ++r) { m_i[r] = -1e30f; l_i[r] = 0.f; }

    for (int t = 0; t <= qt; ++t) {
        const int kv0 = t * 64;
        for (int i = 0; i < 2; ++i) {
            const int idx = i * 256 + tid;
            const int row = idx >> 3, ch = idx & 7;
            *(uint4*)&Ks[row * 72 + ch * 8] =
                *(const uint4*)&qk[(size_t)(b * 2048 + kv0 + row) * 2048 + 1024 + h * 64 + ch * 8];
            *(uint4*)&Vs[row * 72 + ch * 8] =
                *(const uint4*)&vt[((size_t)(bh * 64 + row)) * 2048 + kv0 + ch * 8];
        }
        __syncthreads();

        // S = Q @ K^T : B-frag b[j] = K[key=cb*16+(l&15)][dh=kh*32+g8+j]
        f32x4 sa[4] = {};
        for (int cb = 0; cb < 4; ++cb)
            for (int kh = 0; kh < 2; ++kh) {
                bf16x8 kb = *(const bf16x8*)&Ks[(cb * 16 + mrow) * 72 + kh * 32 + g8];
                sa[cb] = mfma16(qa[kh], kb, sa[cb]);
            }

        // scale + causal mask (only diagonal tile t==qt needs masking)
        float sv[4][4];
        const int qrb = w * 16 + (l >> 4) * 4;
        for (int cb = 0; cb < 4; ++cb)
            for (int r = 0; r < 4; ++r) {
                float xv = sa[cb][r] * 0.125f;
                if (t == qt && (cb * 16 + (l & 15)) > (qrb + r)) xv = -1e30f;
                sv[cb][r] = xv;
            }

        // online softmax per row (row r lives on the 16 lanes sharing l>>4)
        for (int r = 0; r < 4; ++r) {
            float mx = fmaxf(fmaxf(sv[0][r], sv[1][r]), fmaxf(sv[2][r], sv[3][r]));
            for (int off = 1; off < 16; off <<= 1) mx = fmaxf(mx, __shfl_xor(mx, off));
            const float mnew = fmaxf(m_i[r], mx);
            const float alpha = __expf(m_i[r] - mnew);
            m_i[r] = mnew;
            float ps = 0.f;
            for (int cb = 0; cb < 4; ++cb) {
                const float p = __expf(sv[cb][r] - mnew);
                sv[cb][r] = p;
                ps += p;
            }
            for (int off = 1; off < 16; off <<= 1) ps += __shfl_xor(ps, off);
            l_i[r] = l_i[r] * alpha + ps;
            for (int cb = 0; cb < 4; ++cb) o[cb][r] *= alpha;
        }

        // P: C-layout regs -> LDS (own wave slab) -> A-layout frags (m120)
        for (int cb = 0; cb < 4; ++cb)
            for (int r = 0; r < 4; ++r)
                Ps[(w * 16 + (l >> 4) * 4 + r) * 72 + cb * 16 + (l & 15)] = f2b(sv[cb][r]);
        __builtin_amdgcn_s_waitcnt(0xC07F);  // lgkmcnt(0); DS pipe is in-order per wave

        bf16x8 pa[2];
        pa[0] = *(const bf16x8*)&Ps[(w * 16 + mrow) * 72 + g8];
        pa[1] = *(const bf16x8*)&Ps[(w * 16 + mrow) * 72 + 32 + g8];
        // O += P @ V : B-frag b[j] = V[key=kh*32+g8+j][dh=cb*16+(l&15)] = Vs[dh][key]
        for (int cb = 0; cb < 4; ++cb)
            for (int kh = 0; kh < 2; ++kh) {
                bf16x8 vb = *(const bf16x8*)&Vs[(cb * 16 + mrow) * 72 + kh * 32 + g8];
                o[cb] = mfma16(pa[kh], vb, o[cb]);
            }
        __syncthreads();
    }

    // epilogue: attn[token][h*64+dh] = O / l
    for (int r = 0; r < 4; ++r) {
        const float inv = 1.0f / l_i[r];
        const size_t tok = (size_t)(b * 2048 + q0 + w * 16 + (l >> 4) * 4 + r);
        for (int cb = 0; cb < 4; ++cb)
            attn[tok * 1024 + h * 64 + cb * 16 + (l & 15)] = f2b(o[cb][r] * inv);
    }
}

// ---------------------------------------------------------------- launch
extern "C" void kernel_launch(void* const* d_in, const int* in_sizes, int n_in,
                              void* d_out, int out_size, void* d_ws, size_t ws_size,
                              hipStream_t stream) {
    const float* x  = (const float*)d_in[0];
    const float* Wq = (const float*)d_in[1];
    const float* bq = (const float*)d_in[2];
    const float* Wk = (const float*)d_in[3];
    const float* bk = (const float*)d_in[4];
    const float* Wv = (const float*)d_in[5];
    const float* bv = (const float*)d_in[6];
    const float* Wo = (const float*)d_in[7];
    const float* bo = (const float*)d_in[8];
    float* out = (float*)d_out;

    char* ws = (char*)d_ws;
    size_t off = 0;
    auto alloc = [&](size_t bytes) -> void* {
        void* p = ws + off;
        off += (bytes + 255) & ~(size_t)255;
        return p;
    };
    u16*   xb   = (u16*)alloc(8192ull * 1024 * 2);   // x bf16
    u16*   wqkt = (u16*)alloc(2048ull * 1024 * 2);   // [Wq|Wk]^T (N,K)
    u16*   wvt  = (u16*)alloc(1024ull * 1024 * 2);   // Wv^T
    u16*   wot  = (u16*)alloc(1024ull * 1024 * 2);   // Wo^T
    float* bqk  = (float*)alloc(2048ull * 4);
    u16*   qk   = (u16*)alloc(8192ull * 2048 * 2);   // [q|k] (token, 2048)
    u16*   vt   = (u16*)alloc(8192ull * 1024 * 2);   // V^T (B,H,Dh,S)
    u16*   attn = (u16*)alloc(8192ull * 1024 * 2);   // attention out (token, D)

    convert_x<<<8192, 256, 0, stream>>>(x, xb, 8192 * 1024 / 4);
    transpose_w<<<dim3(32, 32, 4), dim3(32, 8), 0, stream>>>(Wq, Wk, Wv, Wo, wqkt, wvt, wot);
    pack_bqk<<<8, 256, 0, stream>>>(bq, bk, bqk);
    gemm_bt<0><<<dim3(64, 16), 256, 0, stream>>>(xb, wqkt, bqk, qk, 8192, 2048, 1024, 2048);
    gemm_bt<2><<<dim3(64, 8), 256, 0, stream>>>(xb, wvt, bv, vt, 8192, 1024, 1024, 0);
    attn_kernel<<<dim3(32, 64), 256, 0, stream>>>(qk, vt, attn);
    gemm_bt<1><<<dim3(64, 8), 256, 0, stream>>>(attn, wot, bo, out, 8192, 1024, 1024, 1024);
}

// Round 2
// 345.303 us; speedup vs baseline: 1.3007x; 1.3007x over previous
//
#include <hip/hip_runtime.h>
#include <hip/hip_bf16.h>

// CausalSelfAttention: B=4, S=2048, D=1024, H=16, Dh=64. fp32 in/out, bf16 MFMA compute.
//
// Pipeline (all on `stream`):
//   1. convert_x: x fp32 -> bf16 (8192x1024)
//   2. transpose_w: Wq|Wk -> wqkt (2048x1024 bf16, N-major), Wv -> wvt, Wo -> wot
//   3. pack_bqk: [bq|bk] -> bqk fp32 (2048)
//   4. gemm<0>: qk = xb @ [Wq|Wk] + bqk   -> bf16 (8192 x 2048)
//   5. gemm<2>: vt = (xb @ Wv + bv)^T     -> bf16 (B,H,Dh,S) scatter epilogue
//   6. attn: causal flash attention, S^T formulation, BM=128/BN=64, 8 waves
//   7. gemm<1>: out = attn @ Wo + bo      -> fp32 d_out

typedef __bf16 bf16x8 __attribute__((ext_vector_type(8)));
typedef float f32x4 __attribute__((ext_vector_type(4)));
typedef unsigned short u16;

__device__ __forceinline__ u16 f2b(float f) {
    __hip_bfloat16 h = __float2bfloat16(f);
    return __builtin_bit_cast(unsigned short, h);
}

__device__ __forceinline__ f32x4 mfma16(bf16x8 a, bf16x8 b, f32x4 c) {
    return __builtin_amdgcn_mfma_f32_16x16x32_bf16(a, b, c, 0, 0, 0);
}

typedef const __attribute__((address_space(1))) unsigned int* gas1_t;
typedef __attribute__((address_space(3))) unsigned int* las3_t;
// Async global->LDS, 16B per lane. LDS dest = wave-uniform base + lane*16 (m104/m108).
__device__ __forceinline__ void gld16(const void* g, void* l) {
    __builtin_amdgcn_global_load_lds((gas1_t)g, (las3_t)l, 16, 0, 0);
}

// ---------------------------------------------------------------- conversions
__global__ __launch_bounds__(256) void convert_x(const float* __restrict__ x,
                                                 u16* __restrict__ xb, int n4) {
    int i = blockIdx.x * 256 + threadIdx.x;
    if (i < n4) {
        float4 v = ((const float4*)x)[i];
        ushort4 u;
        u.x = f2b(v.x); u.y = f2b(v.y); u.z = f2b(v.z); u.w = f2b(v.w);
        ((ushort4*)xb)[i] = u;
    }
}

// W (K=1024 rows, N=1024 cols) fp32 -> Wt (N,K) bf16. z selects matrix.
__global__ __launch_bounds__(256) void transpose_w(const float* __restrict__ Wq,
                                                   const float* __restrict__ Wk,
                                                   const float* __restrict__ Wv,
                                                   const float* __restrict__ Wo,
                                                   u16* __restrict__ wqkt,
                                                   u16* __restrict__ wvt,
                                                   u16* __restrict__ wot) {
    const int z = blockIdx.z;
    const float* src = (z == 0) ? Wq : (z == 1) ? Wk : (z == 2) ? Wv : Wo;
    u16* dst = (z == 0) ? wqkt : (z == 1) ? (wqkt + 1024 * 1024) : (z == 2) ? wvt : wot;
    __shared__ float tile[32][33];
    const int tx = threadIdx.x, ty = threadIdx.y;  // block (32,8)
    const int nbase = blockIdx.x * 32, kbase = blockIdx.y * 32;
    for (int j = 0; j < 4; ++j)
        tile[ty + j * 8][tx] = src[(size_t)(kbase + ty + j * 8) * 1024 + nbase + tx];
    __syncthreads();
    for (int j = 0; j < 4; ++j)
        dst[(size_t)(nbase + ty + j * 8) * 1024 + kbase + tx] = f2b(tile[tx][ty + j * 8]);
}

__global__ __launch_bounds__(256) void pack_bqk(const float* __restrict__ bq,
                                                const float* __restrict__ bk,
                                                float* __restrict__ bqk) {
    int i = blockIdx.x * 256 + threadIdx.x;  // 2048 total
    bqk[i] = (i < 1024) ? bq[i] : bk[i - 1024];
}

// ---------------------------------------------------------------- GEMM (m97-style)
// C(M,N) = A(M,K) @ Bt(N,K)^T + bias. 128x128 tile, BK=32, 256 thr = 4 waves.
// MODE 0: bf16 row-major out. MODE 1: fp32 row-major out. MODE 2: bf16 V^T scatter.
template <int MODE>
__global__ __launch_bounds__(256) void gemm_bt(const u16* __restrict__ A,
                                               const u16* __restrict__ Bt,
                                               const float* __restrict__ bias,
                                               void* __restrict__ Cout,
                                               int M, int N, int K, int ldc) {
    const int tid = threadIdx.x;
    const int l = tid & 63;
    const int w = tid >> 6;
    const int tileM = blockIdx.x * 128;
    const int tileN = blockIdx.y * 128;

    __shared__ u16 As[128 * 32];  // [row][k] stride 32 (contiguous: global_load_lds)
    __shared__ u16 Bs[128 * 32];

    const int srow = l >> 2;
    const int schunk = l & 3;
    const int mrow = l & 15;
    const int g8 = (l >> 4) * 8;
    const int waveM = (w & 1) * 64;
    const int waveN = (w >> 1) * 64;

    f32x4 acc[4][4] = {};

    for (int k0 = 0; k0 < K; k0 += 32) {
        gld16(A + (size_t)(tileM + w * 32 + srow) * K + k0 + schunk * 8, &As[(w * 2) * 512]);
        gld16(A + (size_t)(tileM + w * 32 + 16 + srow) * K + k0 + schunk * 8, &As[(w * 2 + 1) * 512]);
        gld16(Bt + (size_t)(tileN + w * 32 + srow) * K + k0 + schunk * 8, &Bs[(w * 2) * 512]);
        gld16(Bt + (size_t)(tileN + w * 32 + 16 + srow) * K + k0 + schunk * 8, &Bs[(w * 2 + 1) * 512]);
        __syncthreads();

        bf16x8 af[4], bf[4];
        for (int im = 0; im < 4; ++im)
            af[im] = *(const bf16x8*)&As[(waveM + im * 16 + mrow) * 32 + g8];
        for (int in = 0; in < 4; ++in)
            bf[in] = *(const bf16x8*)&Bs[(waveN + in * 16 + mrow) * 32 + g8];
        for (int im = 0; im < 4; ++im)
            for (int in = 0; in < 4; ++in)
                acc[im][in] = mfma16(af[im], bf[in], acc[im][in]);
        __syncthreads();
    }

    // epilogue. C/D layout: row=(l>>4)*4+r, col=l&15  [m89/m91]
    const int rbase = (l >> 4) * 4;
    for (int im = 0; im < 4; ++im) {
        for (int in = 0; in < 4; ++in) {
            const int gm0 = tileM + waveM + im * 16 + rbase;
            const int gn = tileN + waveN + in * 16 + (l & 15);
            const float bv_ = bias[gn];
            if (MODE == 0) {
                u16* out = (u16*)Cout;
                for (int r = 0; r < 4; ++r)
                    out[(size_t)(gm0 + r) * ldc + gn] = f2b(acc[im][in][r] + bv_);
            } else if (MODE == 1) {
                float* out = (float*)Cout;
                for (int r = 0; r < 4; ++r)
                    out[(size_t)(gm0 + r) * ldc + gn] = acc[im][in][r] + bv_;
            } else {
                u16* out = (u16*)Cout;
                const int b = gm0 >> 11, s0 = gm0 & 2047;
                const int h = gn >> 6, dh = gn & 63;
                ushort4 u;
                u.x = f2b(acc[im][in][0] + bv_);
                u.y = f2b(acc[im][in][1] + bv_);
                u.z = f2b(acc[im][in][2] + bv_);
                u.w = f2b(acc[im][in][3] + bv_);
                *(ushort4*)&out[((size_t)((b * 16 + h) * 64 + dh)) * 2048 + s0] = u;
            }
        }
    }
}

// ---------------------------------------------------------------- flash attention (S^T)
// grid (16 qtiles, 64 bh), 512 thr = 8 waves. Wave w owns queries [q0+w*16, +16),
// one query per lane-column (l&15). S^T = K @ Q^T so softmax reduces over regs + 2 shfl.
// O^T = V^T @ P^T accumulated in C-layout (dh rows, query cols).
__global__ __launch_bounds__(512, 6) void attn_kernel(const u16* __restrict__ qk,
                                                      const u16* __restrict__ vt,
                                                      u16* __restrict__ attn) {
    const int qt = 15 - blockIdx.x;  // longest blocks launch first
    const int bh = blockIdx.y;
    const int b = bh >> 4, h = bh & 15;
    const int q0 = qt * 128;
    const int tid = threadIdx.x, l = tid & 63, w = tid >> 6;
    const int q = l & 15;        // query column within wave
    const int g = l >> 4;        // k-group
    const int g8 = g * 8;

    __shared__ u16 Ks[64 * 72];   // [key][dh]
    __shared__ u16 Vs[64 * 72];   // [dh][key]
    __shared__ u16 Ps[128 * 72];  // Q staging, then per-wave P slabs [query][key]

    // stage Q tile (rows q0..q0+127, cols h*64..h*64+63)
    for (int i = 0; i < 2; ++i) {
        const int idx = i * 512 + tid;
        const int row = idx >> 3, ch = idx & 7;
        *(uint4*)&Ps[row * 72 + ch * 8] =
            *(const uint4*)&qk[(size_t)(b * 2048 + q0 + row) * 2048 + h * 64 + ch * 8];
    }
    __syncthreads();
    // Q as B-operand of S^T: b[j] = Q[query=l&15][dh=g*8+j+32*kh]
    bf16x8 qb[2];
    qb[0] = *(const bf16x8*)&Ps[(w * 16 + q) * 72 + g8];
    qb[1] = *(const bf16x8*)&Ps[(w * 16 + q) * 72 + 32 + g8];

    float m2 = -1e30f, l_i = 0.f;  // log2-domain running max / denom (per query = per lane)
    f32x4 o[4] = {};               // O^T: o[cb][r] = O[query=l&15][dh=cb*16+g*4+r]

    const int srow = tid >> 3, sch = tid & 7;  // staging: 64 rows x 8 chunks
    const u16* kg = qk + (size_t)(b * 2048 + srow) * 2048 + 1024 + h * 64 + sch * 8;
    const u16* vg = vt + (size_t)(bh * 64 + srow) * 2048 + sch * 8;
    const int tmax = 2 * qt + 1;
    const int qg = q0 + w * 16 + q;           // global query index for this lane
    const float SCALE_L2E = 0.125f * 1.4426950408889634f;

    uint4 kreg = *(const uint4*)(kg);         // prefetch tile 0
    uint4 vreg = *(const uint4*)(vg);

    for (int t = 0; t <= tmax; ++t) {
        __syncthreads();  // previous tile's compute done
        *(uint4*)&Ks[srow * 72 + sch * 8] = kreg;
        *(uint4*)&Vs[srow * 72 + sch * 8] = vreg;
        __syncthreads();  // staging visible
        if (t < tmax) {   // prefetch next tile (overlaps compute)
            kreg = *(const uint4*)(kg + (size_t)(t + 1) * 64 * 2048);
            vreg = *(const uint4*)(vg + (t + 1) * 64);
        }
        const int kv0 = t * 64;
        if (kv0 <= q0 + w * 16 + 15) {  // wave has unmasked keys in this tile
            // S^T = K @ Q^T : A-frag a[j] = K[key=cb*16+(l&15)][dh=g*8+j+32*kh]
            f32x4 st[4] = {};
            for (int kh = 0; kh < 2; ++kh)
                for (int cb = 0; cb < 4; ++cb) {
                    bf16x8 ka = *(const bf16x8*)&Ks[(cb * 16 + q) * 72 + kh * 32 + g8];
                    st[cb] = mfma16(ka, qb[kh], st[cb]);
                }
            // scale (log2 domain) + causal mask; st[cb][r] is key kv0+cb*16+g*4+r
            for (int cb = 0; cb < 4; ++cb)
                for (int r = 0; r < 4; ++r) {
                    const int key = kv0 + cb * 16 + g * 4 + r;
                    float xv = st[cb][r] * SCALE_L2E;
                    st[cb][r] = (key > qg) ? -1e30f : xv;
                }
            // online softmax: reduce 16 regs then 2 shuffles (lanes sharing l&15)
            float mx = st[0][0];
            for (int cb = 0; cb < 4; ++cb)
                for (int r = 0; r < 4; ++r) mx = fmaxf(mx, st[cb][r]);
            mx = fmaxf(mx, __shfl_xor(mx, 16));
            mx = fmaxf(mx, __shfl_xor(mx, 32));
            const float mnew = fmaxf(m2, mx);
            const float alpha = __builtin_amdgcn_exp2f(m2 - mnew);
            m2 = mnew;
            float ps = 0.f;
            for (int cb = 0; cb < 4; ++cb)
                for (int r = 0; r < 4; ++r) {
                    const float p = __builtin_amdgcn_exp2f(st[cb][r] - mnew);
                    st[cb][r] = p;
                    ps += p;
                }
            ps += __shfl_xor(ps, 16);
            ps += __shfl_xor(ps, 32);
            l_i = l_i * alpha + ps;
            for (int cb = 0; cb < 4; ++cb) o[cb] *= alpha;
            // P^T C-regs -> Ps[query][key] (r=0..3 consecutive keys -> ds_write_b64)
            for (int cb = 0; cb < 4; ++cb) {
                ushort4 u;
                u.x = f2b(st[cb][0]); u.y = f2b(st[cb][1]);
                u.z = f2b(st[cb][2]); u.w = f2b(st[cb][3]);
                *(ushort4*)&Ps[(w * 16 + q) * 72 + cb * 16 + g * 4] = u;
            }
            __builtin_amdgcn_s_waitcnt(0xC07F);  // lgkmcnt(0); DS in-order per wave
            // O^T += V^T @ P^T : A-frag V^T[dh=cb*16+(l&15)][key], B-frag P[query][key]
            for (int kh = 0; kh < 2; ++kh) {
                bf16x8 pb = *(const bf16x8*)&Ps[(w * 16 + q) * 72 + kh * 32 + g8];
                for (int cb = 0; cb < 4; ++cb) {
                    bf16x8 va = *(const bf16x8*)&Vs[(cb * 16 + q) * 72 + kh * 32 + g8];
                    o[cb] = mfma16(va, pb, o[cb]);
                }
            }
        }
    }

    // epilogue: attn[token][h*64+dh], token = per-lane, dh = cb*16+g*4+r contiguous
    const float inv = 1.0f / l_i;
    const size_t tok = (size_t)(b * 2048 + q0 + w * 16 + q);
    for (int cb = 0; cb < 4; ++cb) {
        ushort4 u;
        u.x = f2b(o[cb][0] * inv); u.y = f2b(o[cb][1] * inv);
        u.z = f2b(o[cb][2] * inv); u.w = f2b(o[cb][3] * inv);
        *(ushort4*)&attn[tok * 1024 + h * 64 + cb * 16 + g * 4] = u;
    }
}

// ---------------------------------------------------------------- launch
extern "C" void kernel_launch(void* const* d_in, const int* in_sizes, int n_in,
                              void* d_out, int out_size, void* d_ws, size_t ws_size,
                              hipStream_t stream) {
    const float* x  = (const float*)d_in[0];
    const float* Wq = (const float*)d_in[1];
    const float* bq = (const float*)d_in[2];
    const float* Wk = (const float*)d_in[3];
    const float* bk = (const float*)d_in[4];
    const float* Wv = (const float*)d_in[5];
    const float* bv = (const float*)d_in[6];
    const float* Wo = (const float*)d_in[7];
    const float* bo = (const float*)d_in[8];
    float* out = (float*)d_out;

    char* ws = (char*)d_ws;
    size_t off = 0;
    auto alloc = [&](size_t bytes) -> void* {
        void* p = ws + off;
        off += (bytes + 255) & ~(size_t)255;
        return p;
    };
    u16*   xb   = (u16*)alloc(8192ull * 1024 * 2);   // x bf16
    u16*   wqkt = (u16*)alloc(2048ull * 1024 * 2);   // [Wq|Wk]^T (N,K)
    u16*   wvt  = (u16*)alloc(1024ull * 1024 * 2);   // Wv^T
    u16*   wot  = (u16*)alloc(1024ull * 1024 * 2);   // Wo^T
    float* bqk  = (float*)alloc(2048ull * 4);
    u16*   qk   = (u16*)alloc(8192ull * 2048 * 2);   // [q|k] (token, 2048)
    u16*   vt   = (u16*)alloc(8192ull * 1024 * 2);   // V^T (B,H,Dh,S)
    u16*   attn = (u16*)alloc(8192ull * 1024 * 2);   // attention out (token, D)

    convert_x<<<8192, 256, 0, stream>>>(x, xb, 8192 * 1024 / 4);
    transpose_w<<<dim3(32, 32, 4), dim3(32, 8), 0, stream>>>(Wq, Wk, Wv, Wo, wqkt, wvt, wot);
    pack_bqk<<<8, 256, 0, stream>>>(bq, bk, bqk);
    gemm_bt<0><<<dim3(64, 16), 256, 0, stream>>>(xb, wqkt, bqk, qk, 8192, 2048, 1024, 2048);
    gemm_bt<2><<<dim3(64, 8), 256, 0, stream>>>(xb, wvt, bv, vt, 8192, 1024, 1024, 0);
    attn_kernel<<<dim3(16, 64), 512, 0, stream>>>(qk, vt, attn);
    gemm_bt<1><<<dim3(64, 8), 256, 0, stream>>>(attn, wot, bo, out, 8192, 1024, 1024, 1024);
}

// Round 4
// 316.120 us; speedup vs baseline: 1.4208x; 1.0923x over previous
//
#include <hip/hip_runtime.h>
#include <hip/hip_bf16.h>

// CausalSelfAttention: B=4, S=2048, D=1024, H=16, Dh=64. fp32 in/out, bf16 MFMA compute.
//
// Pipeline (all on `stream`):
//   1. convert_x: x fp32 -> bf16 (8192x1024)
//   2. transpose_w: Wq|Wk|Wv -> wqkvt (3072x1024 bf16, N-major), Wo -> wot
//   3. pack_bqkv: [bq|bk|bv] -> fp32 (3072)
//   4. gemm<0>: qkv = xb @ [Wq|Wk|Wv] + b  -> qk bf16 (8192x2048) + vt (B,H,Dh,S) scatter
//   5. attn: causal flash attention, S^T form, 32 q/wave, paired q-tiles for balance
//   6. gemm<1>: out = attn @ Wo + bo       -> fp32 d_out

typedef __bf16 bf16x8 __attribute__((ext_vector_type(8)));
typedef float f32x4 __attribute__((ext_vector_type(4)));
typedef unsigned short u16;

__device__ __forceinline__ u16 f2b(float f) {
    __hip_bfloat16 h = __float2bfloat16(f);
    return __builtin_bit_cast(unsigned short, h);
}

__device__ __forceinline__ f32x4 mfma16(bf16x8 a, bf16x8 b, f32x4 c) {
    return __builtin_amdgcn_mfma_f32_16x16x32_bf16(a, b, c, 0, 0, 0);
}

typedef const __attribute__((address_space(1))) unsigned int* gas1_t;
typedef __attribute__((address_space(3))) unsigned int* las3_t;
__device__ __forceinline__ void gld16(const void* g, void* l) {
    __builtin_amdgcn_global_load_lds((gas1_t)g, (las3_t)l, 16, 0, 0);
}

// ---------------------------------------------------------------- conversions
__global__ __launch_bounds__(256) void convert_x(const float* __restrict__ x,
                                                 u16* __restrict__ xb, int n4) {
    int i = blockIdx.x * 256 + threadIdx.x;
    if (i < n4) {
        float4 v = ((const float4*)x)[i];
        ushort4 u;
        u.x = f2b(v.x); u.y = f2b(v.y); u.z = f2b(v.z); u.w = f2b(v.w);
        ((ushort4*)xb)[i] = u;
    }
}

// W (K=1024 rows, N=1024 cols) fp32 -> Wt (N,K) bf16. z selects matrix.
__global__ __launch_bounds__(256) void transpose_w(const float* __restrict__ Wq,
                                                   const float* __restrict__ Wk,
                                                   const float* __restrict__ Wv,
                                                   const float* __restrict__ Wo,
                                                   u16* __restrict__ wqkvt,
                                                   u16* __restrict__ wot) {
    const int z = blockIdx.z;
    const float* src = (z == 0) ? Wq : (z == 1) ? Wk : (z == 2) ? Wv : Wo;
    u16* dst = (z == 3) ? wot : (wqkvt + (size_t)z * 1024 * 1024);
    __shared__ float tile[32][33];
    const int tx = threadIdx.x, ty = threadIdx.y;  // block (32,8)
    const int nbase = blockIdx.x * 32, kbase = blockIdx.y * 32;
    for (int j = 0; j < 4; ++j)
        tile[ty + j * 8][tx] = src[(size_t)(kbase + ty + j * 8) * 1024 + nbase + tx];
    __syncthreads();
    for (int j = 0; j < 4; ++j)
        dst[(size_t)(nbase + ty + j * 8) * 1024 + kbase + tx] = f2b(tile[tx][ty + j * 8]);
}

__global__ __launch_bounds__(256) void pack_bqkv(const float* __restrict__ bq,
                                                 const float* __restrict__ bk,
                                                 const float* __restrict__ bv,
                                                 float* __restrict__ bqkv) {
    int i = blockIdx.x * 256 + threadIdx.x;  // 3072 total
    bqkv[i] = (i < 1024) ? bq[i] : (i < 2048) ? bk[i - 1024] : bv[i - 2048];
}

// ---------------------------------------------------------------- GEMM (m97-style)
// C(M,N) = A(M,K) @ Bt(N,K)^T + bias. 128x128 tile, BK=32, 256 thr = 4 waves.
// MODE 0: QKV-combined: cols <2048 -> bf16 row-major qk; cols >=2048 -> V^T scatter.
// MODE 1: fp32 row-major out.
template <int MODE>
__global__ __launch_bounds__(256) void gemm_bt(const u16* __restrict__ A,
                                               const u16* __restrict__ Bt,
                                               const float* __restrict__ bias,
                                               void* __restrict__ Cout,
                                               void* __restrict__ Cout2,
                                               int M, int N, int K, int ldc) {
    const int tid = threadIdx.x;
    const int l = tid & 63;
    const int w = tid >> 6;
    const int tileM = blockIdx.x * 128;
    const int tileN = blockIdx.y * 128;

    __shared__ u16 As[128 * 32];
    __shared__ u16 Bs[128 * 32];

    const int srow = l >> 2;
    const int schunk = l & 3;
    const int mrow = l & 15;
    const int g8 = (l >> 4) * 8;
    const int waveM = (w & 1) * 64;
    const int waveN = (w >> 1) * 64;

    f32x4 acc[4][4] = {};

    for (int k0 = 0; k0 < K; k0 += 32) {
        gld16(A + (size_t)(tileM + w * 32 + srow) * K + k0 + schunk * 8, &As[(w * 2) * 512]);
        gld16(A + (size_t)(tileM + w * 32 + 16 + srow) * K + k0 + schunk * 8, &As[(w * 2 + 1) * 512]);
        gld16(Bt + (size_t)(tileN + w * 32 + srow) * K + k0 + schunk * 8, &Bs[(w * 2) * 512]);
        gld16(Bt + (size_t)(tileN + w * 32 + 16 + srow) * K + k0 + schunk * 8, &Bs[(w * 2 + 1) * 512]);
        __syncthreads();

        bf16x8 af[4], bf[4];
        for (int im = 0; im < 4; ++im)
            af[im] = *(const bf16x8*)&As[(waveM + im * 16 + mrow) * 32 + g8];
        for (int in = 0; in < 4; ++in)
            bf[in] = *(const bf16x8*)&Bs[(waveN + in * 16 + mrow) * 32 + g8];
        for (int im = 0; im < 4; ++im)
            for (int in = 0; in < 4; ++in)
                acc[im][in] = mfma16(af[im], bf[in], acc[im][in]);
        __syncthreads();
    }

    // epilogue. C/D layout: row=(l>>4)*4+r, col=l&15  [m89/m91]
    const int rbase = (l >> 4) * 4;
    for (int im = 0; im < 4; ++im) {
        for (int in = 0; in < 4; ++in) {
            const int gm0 = tileM + waveM + im * 16 + rbase;
            const int gn = tileN + waveN + in * 16 + (l & 15);
            const float bv_ = bias[gn];
            if (MODE == 1) {
                float* out = (float*)Cout;
                for (int r = 0; r < 4; ++r)
                    out[(size_t)(gm0 + r) * ldc + gn] = acc[im][in][r] + bv_;
            } else if (tileN < 2048) {
                u16* out = (u16*)Cout;  // qk, row-major (token, 2048)
                for (int r = 0; r < 4; ++r)
                    out[(size_t)(gm0 + r) * 2048 + gn] = f2b(acc[im][in][r] + bv_);
            } else {
                u16* out = (u16*)Cout2;  // V^T scatter (B,H,Dh,S)
                const int b = gm0 >> 11, s0 = gm0 & 2047;
                const int gn2 = gn - 2048;
                const int h = gn2 >> 6, dh = gn2 & 63;
                ushort4 u;
                u.x = f2b(acc[im][in][0] + bv_);
                u.y = f2b(acc[im][in][1] + bv_);
                u.z = f2b(acc[im][in][2] + bv_);
                u.w = f2b(acc[im][in][3] + bv_);
                *(ushort4*)&out[((size_t)((b * 16 + h) * 64 + dh)) * 2048 + s0] = u;
            }
        }
    }
}

// ---------------------------------------------------------------- flash attention (S^T, 32q/wave)
// grid (8, 64), 256 thr = 4 waves. Each block processes q-tile PAIR (15-bx, bx):
// every block does exactly 34 key-tile rounds -> perfect CU load balance.
// Wave w owns 32 queries [q0+w*32, +32) as two 16-col groups; K/V LDS fragments
// are reused across both groups (halves LDS reads per query vs 16q/wave).
__global__ __launch_bounds__(256, 2) void attn_kernel(const u16* __restrict__ qk,
                                                      const u16* __restrict__ vt,
                                                      u16* __restrict__ attn) {
    const int bh = blockIdx.y;
    const int b = bh >> 4, h = bh & 15;
    const int tid = threadIdx.x, l = tid & 63, w = tid >> 6;
    const int q = l & 15;   // query column within group
    const int g = l >> 4;   // k-group
    const int g8 = g * 8;

    __shared__ u16 Ks[64 * 72];   // [key][dh]
    __shared__ u16 Vs[64 * 72];   // [dh][key]
    __shared__ u16 Ps[128 * 72];  // Q staging, then per-wave P slabs [query][key]

    const int srow = tid >> 3, sch = tid & 7;  // staging: 32 rows x 8 chunks, x2 passes
    const u16* kgb = qk + (size_t)(b * 2048 + srow) * 2048 + 1024 + h * 64 + sch * 8;
    const u16* vgb = vt + (size_t)(bh * 64 + srow) * 2048 + sch * 8;
    const float SCALE_L2E = 0.125f * 1.4426950408889634f;

    for (int phase = 0; phase < 2; ++phase) {
        const int qt = phase == 0 ? (15 - (int)blockIdx.x) : (int)blockIdx.x;
        const int q0 = qt * 128;

        __syncthreads();  // Ps free (prev phase compute done)
        // stage Q tile (128 rows x 64 cols): 4 passes of 256 thr x 16B
        for (int i = 0; i < 4; ++i) {
            const int idx = i * 256 + tid;
            const int row = idx >> 3, ch = idx & 7;
            *(uint4*)&Ps[row * 72 + ch * 8] =
                *(const uint4*)&qk[(size_t)(b * 2048 + q0 + row) * 2048 + h * 64 + ch * 8];
        }
        __syncthreads();
        bf16x8 qb[2][2];  // [col-group][kh]
        for (int c = 0; c < 2; ++c) {
            qb[c][0] = *(const bf16x8*)&Ps[(w * 32 + c * 16 + q) * 72 + g8];
            qb[c][1] = *(const bf16x8*)&Ps[(w * 32 + c * 16 + q) * 72 + 32 + g8];
        }

        float m2[2] = {-1e30f, -1e30f}, li[2] = {0.f, 0.f};
        f32x4 o[2][4] = {};
        const int tmax = 2 * qt + 1;

        uint4 kreg[2], vreg[2];  // prefetch tile 0
        for (int j = 0; j < 2; ++j) {
            kreg[j] = *(const uint4*)(kgb + (size_t)(j * 32) * 2048);
            vreg[j] = *(const uint4*)(vgb + (size_t)(j * 32) * 2048);
        }

        for (int t = 0; t <= tmax; ++t) {
            __syncthreads();  // prev tile compute done
            for (int j = 0; j < 2; ++j) {
                *(uint4*)&Ks[(srow + j * 32) * 72 + sch * 8] = kreg[j];
                *(uint4*)&Vs[(srow + j * 32) * 72 + sch * 8] = vreg[j];
            }
            __syncthreads();  // staging visible
            if (t < tmax) {   // prefetch next tile (overlaps compute)
                for (int j = 0; j < 2; ++j) {
                    // K rows are tokens: advance (t+1)*64 rows.
                    kreg[j] = *(const uint4*)(kgb + (size_t)((t + 1) * 64 + j * 32) * 2048);
                    // V^T rows are dh: key tile advances along COLUMNS (+64 elems/tile).
                    vreg[j] = *(const uint4*)(vgb + (size_t)(j * 32) * 2048 + (t + 1) * 64);
                }
            }
            const int kv0 = t * 64;
            if (kv0 > q0 + w * 32 + 31) continue;  // whole wave masked this tile

            // S^T = K @ Q^T : K A-frags shared across both query groups
            f32x4 st[2][4] = {};
            for (int kh = 0; kh < 2; ++kh)
                for (int cb = 0; cb < 4; ++cb) {
                    bf16x8 ka = *(const bf16x8*)&Ks[(cb * 16 + q) * 72 + kh * 32 + g8];
                    st[0][cb] = mfma16(ka, qb[0][kh], st[0][cb]);
                    st[1][cb] = mfma16(ka, qb[1][kh], st[1][cb]);
                }
            for (int c = 0; c < 2; ++c) {
                const int qg = q0 + w * 32 + c * 16 + q;
                for (int cb = 0; cb < 4; ++cb)
                    for (int r = 0; r < 4; ++r) {
                        const int key = kv0 + cb * 16 + g * 4 + r;
                        const float xv = st[c][cb][r] * SCALE_L2E;
                        st[c][cb][r] = (key > qg) ? -1e30f : xv;
                    }
                float mx = st[c][0][0];
                for (int cb = 0; cb < 4; ++cb)
                    for (int r = 0; r < 4; ++r) mx = fmaxf(mx, st[c][cb][r]);
                mx = fmaxf(mx, __shfl_xor(mx, 16));
                mx = fmaxf(mx, __shfl_xor(mx, 32));
                const float mnew = fmaxf(m2[c], mx);
                const float alpha = __builtin_amdgcn_exp2f(m2[c] - mnew);
                m2[c] = mnew;
                float ps = 0.f;
                for (int cb = 0; cb < 4; ++cb)
                    for (int r = 0; r < 4; ++r) {
                        const float p = __builtin_amdgcn_exp2f(st[c][cb][r] - mnew);
                        st[c][cb][r] = p;
                        ps += p;
                    }
                ps += __shfl_xor(ps, 16);
                ps += __shfl_xor(ps, 32);
                li[c] = li[c] * alpha + ps;
                for (int cb = 0; cb < 4; ++cb) o[c][cb] *= alpha;
                // P^T C-regs -> Ps[query][key] (r=0..3 consecutive keys -> b64)
                for (int cb = 0; cb < 4; ++cb) {
                    ushort4 u;
                    u.x = f2b(st[c][cb][0]); u.y = f2b(st[c][cb][1]);
                    u.z = f2b(st[c][cb][2]); u.w = f2b(st[c][cb][3]);
                    *(ushort4*)&Ps[(w * 32 + c * 16 + q) * 72 + cb * 16 + g * 4] = u;
                }
            }
            __builtin_amdgcn_s_waitcnt(0xC07F);  // lgkmcnt(0); DS in-order per wave
            // O^T += V^T @ P^T : V A-frags shared across both query groups
            for (int kh = 0; kh < 2; ++kh) {
                bf16x8 pb0 = *(const bf16x8*)&Ps[(w * 32 + q) * 72 + kh * 32 + g8];
                bf16x8 pb1 = *(const bf16x8*)&Ps[(w * 32 + 16 + q) * 72 + kh * 32 + g8];
                for (int cb = 0; cb < 4; ++cb) {
                    bf16x8 va = *(const bf16x8*)&Vs[(cb * 16 + q) * 72 + kh * 32 + g8];
                    o[0][cb] = mfma16(va, pb0, o[0][cb]);
                    o[1][cb] = mfma16(va, pb1, o[1][cb]);
                }
            }
        }

        // epilogue: attn[token][h*64+dh], dh = cb*16+g*4+r contiguous
        for (int c = 0; c < 2; ++c) {
            const float inv = 1.0f / li[c];
            const size_t tok = (size_t)(b * 2048 + q0 + w * 32 + c * 16 + q);
            for (int cb = 0; cb < 4; ++cb) {
                ushort4 u;
                u.x = f2b(o[c][cb][0] * inv); u.y = f2b(o[c][cb][1] * inv);
                u.z = f2b(o[c][cb][2] * inv); u.w = f2b(o[c][cb][3] * inv);
                *(ushort4*)&attn[tok * 1024 + h * 64 + cb * 16 + g * 4] = u;
            }
        }
    }
}

// ---------------------------------------------------------------- launch
extern "C" void kernel_launch(void* const* d_in, const int* in_sizes, int n_in,
                              void* d_out, int out_size, void* d_ws, size_t ws_size,
                              hipStream_t stream) {
    const float* x  = (const float*)d_in[0];
    const float* Wq = (const float*)d_in[1];
    const float* bq = (const float*)d_in[2];
    const float* Wk = (const float*)d_in[3];
    const float* bk = (const float*)d_in[4];
    const float* Wv = (const float*)d_in[5];
    const float* bv = (const float*)d_in[6];
    const float* Wo = (const float*)d_in[7];
    const float* bo = (const float*)d_in[8];
    float* out = (float*)d_out;

    char* ws = (char*)d_ws;
    size_t off = 0;
    auto alloc = [&](size_t bytes) -> void* {
        void* p = ws + off;
        off += (bytes + 255) & ~(size_t)255;
        return p;
    };
    u16*   xb    = (u16*)alloc(8192ull * 1024 * 2);   // x bf16
    u16*   wqkvt = (u16*)alloc(3072ull * 1024 * 2);   // [Wq|Wk|Wv]^T (N,K)
    u16*   wot   = (u16*)alloc(1024ull * 1024 * 2);   // Wo^T
    float* bqkv  = (float*)alloc(3072ull * 4);
    u16*   qk    = (u16*)alloc(8192ull * 2048 * 2);   // [q|k] (token, 2048)
    u16*   vt    = (u16*)alloc(8192ull * 1024 * 2);   // V^T (B,H,Dh,S)
    u16*   attn  = (u16*)alloc(8192ull * 1024 * 2);   // attention out (token, D)

    convert_x<<<8192, 256, 0, stream>>>(x, xb, 8192 * 1024 / 4);
    transpose_w<<<dim3(32, 32, 4), dim3(32, 8), 0, stream>>>(Wq, Wk, Wv, Wo, wqkvt, wot);
    pack_bqkv<<<12, 256, 0, stream>>>(bq, bk, bv, bqkv);
    gemm_bt<0><<<dim3(64, 24), 256, 0, stream>>>(xb, wqkvt, bqkv, qk, vt, 8192, 3072, 1024, 0);
    attn_kernel<<<dim3(8, 64), 256, 0, stream>>>(qk, vt, attn);
    gemm_bt<1><<<dim3(64, 8), 256, 0, stream>>>(attn, wot, bo, out, nullptr, 8192, 1024, 1024, 1024);
}